// Round 8
// baseline (290.367 us; speedup 1.0000x reference)
//
#include <hip/hip_runtime.h>

#define DD 128
#define AA 64
#define SS 96    // fused sub-row stride in floats: 32 (64 bf16 logit) + 64 (128 bf16 msg)

static inline int idiv_up(int a, int b) { return (a + b - 1) / b; }

__device__ __forceinline__ unsigned short f2bf(float f) {
    unsigned u = __float_as_uint(f);
    u += 0x7fff + ((u >> 16) & 1);          // round-to-nearest-even
    return (unsigned short)(u >> 16);
}
__device__ __forceinline__ float bf2f(unsigned short h) {
    return __uint_as_float(((unsigned)h) << 16);
}

// ---------------------------------------------------------------------------
// Fused projections, single d-pass with 3 concurrent weight streams.
//  type 0: hidden -> subrows [64 bf16 logit (Ws) | 128 bf16 msg (Wh)]
//  type 1: rela   -> hrWr f32 (Wr) + relaWh f32 (Wh)
//  type 2: rela[q_rel] -> hqrWqr f32 (Wqr + bqr)   [streams 1,2 discarded]
// Per d-step: 1 LDS float4 + 3 independent global float4 (L1-resident W)
// + 48 FMAs; unroll 4 => 12 loads in flight.
// ---------------------------------------------------------------------------
__global__ __launch_bounds__(256)
void proj_all_kernel(const float* __restrict__ hidden,
                     const float* __restrict__ rela,
                     const int* __restrict__ q_rel,
                     const float* __restrict__ Ws,
                     const float* __restrict__ Wr,
                     const float* __restrict__ Wqr,
                     const float* __restrict__ bqr,
                     const float* __restrict__ Wh,
                     float* __restrict__ subrows,
                     float* __restrict__ hrWr,
                     float* __restrict__ relaWh,
                     float* __restrict__ hqrWqr,
                     int N, int NR, int B, int nA, int nB) {
    __shared__ float lht[128 * 64];    // transposed source tile [d][row]
    const int t = threadIdx.x;
    const int bid = blockIdx.x;
    int type, rbase, nrows;
    const float* src;
    if (bid < nA)           { type = 0; rbase = bid * 64;             nrows = N;  src = hidden; }
    else if (bid < nA + nB) { type = 1; rbase = (bid - nA) * 64;      nrows = NR; src = rela; }
    else                    { type = 2; rbase = (bid - nA - nB) * 64; nrows = B;  src = rela; }

    // stage source tile (transposed)
    const int row = t & 63;
    const int d0 = (t >> 6) * 32;
    const int gr = rbase + row;
    const float* srow = nullptr;
    if (gr < nrows) {
        const int sr = (type == 2) ? q_rel[gr] : gr;
        srow = src + (long)sr * DD;
    }
    #pragma unroll
    for (int j = 0; j < 8; ++j) {
        float4 v = make_float4(0.f, 0.f, 0.f, 0.f);
        if (srow) v = *(const float4*)&srow[d0 + j * 4];
        lht[(d0 + j * 4 + 0) * 64 + row] = v.x;
        lht[(d0 + j * 4 + 1) * 64 + row] = v.y;
        lht[(d0 + j * 4 + 2) * 64 + row] = v.z;
        lht[(d0 + j * 4 + 3) * 64 + row] = v.w;
    }
    __syncthreads();

    const int r0 = (t & 15) * 4;
    const int c0 = (t >> 4) * 4;

    const float* W0 = ((type == 0) ? Ws : (type == 1) ? Wr : Wqr) + c0;  // ld 64
    const float* W1 = Wh + c0;                                            // ld 128
    const float* W2 = Wh + 64 + c0;                                       // ld 128

    float acc[4][12] = {};
    #pragma unroll 4
    for (int d = 0; d < 128; ++d) {
        const float4 hv  = *(const float4*)&lht[d * 64 + r0];
        const float4 wv0 = *(const float4*)&W0[(long)d * 64];
        const float4 wv1 = *(const float4*)&W1[(long)d * 128];
        const float4 wv2 = *(const float4*)&W2[(long)d * 128];
        const float h[4] = { hv.x, hv.y, hv.z, hv.w };
        #pragma unroll
        for (int i = 0; i < 4; ++i) {
            acc[i][0]  = fmaf(h[i], wv0.x, acc[i][0]);
            acc[i][1]  = fmaf(h[i], wv0.y, acc[i][1]);
            acc[i][2]  = fmaf(h[i], wv0.z, acc[i][2]);
            acc[i][3]  = fmaf(h[i], wv0.w, acc[i][3]);
            acc[i][4]  = fmaf(h[i], wv1.x, acc[i][4]);
            acc[i][5]  = fmaf(h[i], wv1.y, acc[i][5]);
            acc[i][6]  = fmaf(h[i], wv1.z, acc[i][6]);
            acc[i][7]  = fmaf(h[i], wv1.w, acc[i][7]);
            acc[i][8]  = fmaf(h[i], wv2.x, acc[i][8]);
            acc[i][9]  = fmaf(h[i], wv2.y, acc[i][9]);
            acc[i][10] = fmaf(h[i], wv2.z, acc[i][10]);
            acc[i][11] = fmaf(h[i], wv2.w, acc[i][11]);
        }
    }

    #pragma unroll
    for (int i = 0; i < 4; ++i) {
        const int orow = rbase + r0 + i;
        if (orow >= nrows) continue;
        if (type == 0) {
            float* srw = subrows + (long)orow * SS;
            ushort4 o0, o1, o2;
            o0.x = f2bf(acc[i][0]);  o0.y = f2bf(acc[i][1]);
            o0.z = f2bf(acc[i][2]);  o0.w = f2bf(acc[i][3]);
            o1.x = f2bf(acc[i][4]);  o1.y = f2bf(acc[i][5]);
            o1.z = f2bf(acc[i][6]);  o1.w = f2bf(acc[i][7]);
            o2.x = f2bf(acc[i][8]);  o2.y = f2bf(acc[i][9]);
            o2.z = f2bf(acc[i][10]); o2.w = f2bf(acc[i][11]);
            *(ushort4*)((unsigned short*)srw + c0) = o0;
            *(ushort4*)((unsigned short*)(srw + 32) + c0) = o1;
            *(ushort4*)((unsigned short*)(srw + 32) + 64 + c0) = o2;
        } else if (type == 1) {
            *(float4*)&hrWr[(long)orow * 64 + c0] =
                make_float4(acc[i][0], acc[i][1], acc[i][2], acc[i][3]);
            *(float4*)&relaWh[(long)orow * 128 + c0] =
                make_float4(acc[i][4], acc[i][5], acc[i][6], acc[i][7]);
            *(float4*)&relaWh[(long)orow * 128 + 64 + c0] =
                make_float4(acc[i][8], acc[i][9], acc[i][10], acc[i][11]);
        } else {
            const float4 bq = *(const float4*)&bqr[c0];
            *(float4*)&hqrWqr[(long)orow * 64 + c0] =
                make_float4(acc[i][0] + bq.x, acc[i][1] + bq.y,
                            acc[i][2] + bq.z, acc[i][3] + bq.w);
        }
    }
}

// ---------- histogram of obj: 4 edges/thread via 6 coalesced int4 loads ----------
__global__ void hist_kernel(const int* __restrict__ edges, int* deg, int E) {
    const int e0 = (blockIdx.x * blockDim.x + threadIdx.x) * 4;
    if (e0 >= E) return;
    if (e0 + 3 < E) {
        const int4* p = (const int4*)&edges[(long)e0 * 6];
        const int4 j1 = p[1], j2 = p[2], j4 = p[4], j5 = p[5];
        atomicAdd(&deg[j1.y], 1);   // edge e0+0: idx 5
        atomicAdd(&deg[j2.w], 1);   // edge e0+1: idx 11
        atomicAdd(&deg[j4.y], 1);   // edge e0+2: idx 17
        atomicAdd(&deg[j5.w], 1);   // edge e0+3: idx 23
    } else {
        for (int e = e0; e < E; ++e) atomicAdd(&deg[edges[(long)e * 6 + 5]], 1);
    }
}

// ---------------------------------------------------------------------------
// One-dispatch scan: per-block local exclusive scan of its 1024-chunk -> loff
// (+ seed cur); last-finished block prefix-scans chunk totals -> bsumx.
// ---------------------------------------------------------------------------
__global__ __launch_bounds__(256)
void scan_kernel(const int* __restrict__ deg, int* __restrict__ loff,
                 int* __restrict__ cur, int* __restrict__ bsum,
                 int* __restrict__ bsumx, int* __restrict__ done,
                 int n, int nb) {
    __shared__ int tsum[256];
    __shared__ int lastFlag;
    const int t = threadIdx.x;
    const int b = blockIdx.x;
    const int base = b * 1024 + t * 4;
    int v[4];
    int s = 0;
    #pragma unroll
    for (int j = 0; j < 4; ++j) {
        v[j] = (base + j < n) ? deg[base + j] : 0;
        s += v[j];
    }
    tsum[t] = s;
    __syncthreads();
    for (int o = 1; o < 256; o <<= 1) {
        const int x = (t >= o) ? tsum[t - o] : 0;
        __syncthreads();
        tsum[t] += x;
        __syncthreads();
    }
    int run = (t > 0) ? tsum[t - 1] : 0;
    #pragma unroll
    for (int j = 0; j < 4; ++j) {
        if (base + j < n) { loff[base + j] = run; cur[base + j] = run; }
        run += v[j];
    }
    if (t == 255) {
        bsum[b] = tsum[255];
        __threadfence();
    }
    __syncthreads();
    if (t == 0) lastFlag = (atomicAdd(done, 1) == nb - 1);
    __syncthreads();
    if (lastFlag && t < 64) {
        __threadfence();
        const int val = (t < nb) ? bsum[t] : 0;
        int inc = val;
        #pragma unroll
        for (int o = 1; o < 64; o <<= 1) {
            const int x = __shfl_up(inc, o, 64);
            if (t >= o) inc += x;
        }
        if (t < nb) bsumx[t] = inc - val;
    }
}

// ---------- scatter: 4 edges/thread, coalesced int4 reads ----------
__global__ void scatter_kernel(const int* __restrict__ edges, int* cur,
                               const int* __restrict__ bsumx,
                               int2* __restrict__ recs, int E) {
    const int e0 = (blockIdx.x * blockDim.x + threadIdx.x) * 4;
    if (e0 >= E) return;
    if (e0 + 3 < E) {
        const int4* p = (const int4*)&edges[(long)e0 * 6];
        const int4 j0 = p[0], j1 = p[1], j2 = p[2], j3 = p[3], j4 = p[4], j5 = p[5];
        // edge k fields: ridx=6k+0, rel=6k+2, sub=6k+4, obj=6k+5
        {   // e0+0: 0,2,4,5
            const int pos = bsumx[j1.y >> 10] + atomicAdd(&cur[j1.y], 1);
            recs[pos] = make_int2(j1.x, j0.z | (j0.x << 16));
        }
        {   // e0+1: 6,8,10,11
            const int pos = bsumx[j2.w >> 10] + atomicAdd(&cur[j2.w], 1);
            recs[pos] = make_int2(j2.z, j2.x | (j1.z << 16));
        }
        {   // e0+2: 12,14,16,17
            const int pos = bsumx[j4.y >> 10] + atomicAdd(&cur[j4.y], 1);
            recs[pos] = make_int2(j4.x, j3.z | (j3.x << 16));
        }
        {   // e0+3: 18,20,22,23
            const int pos = bsumx[j5.w >> 10] + atomicAdd(&cur[j5.w], 1);
            recs[pos] = make_int2(j5.z, j5.x | (j4.z << 16));
        }
    } else {
        for (int e = e0; e < E; ++e) {
            const int* ed = edges + (long)e * 6;
            const int obj = ed[5];
            const int pos = bsumx[obj >> 10] + atomicAdd(&cur[obj], 1);
            recs[pos] = make_int2(ed[4], ed[2] | (ed[0] << 16));
        }
    }
}

// ---------------------------------------------------------------------------
// Gather: one wave per destination node, 16 lanes per edge, 8 edges in flight.
// ---------------------------------------------------------------------------
__global__ __launch_bounds__(256)
void gather_kernel(const int2* __restrict__ recs,
                   const int* __restrict__ loff,
                   const int* __restrict__ bsumx,
                   const float* __restrict__ subrows,
                   const float* __restrict__ hrWr,
                   const float* __restrict__ hqrWqr,
                   const float* __restrict__ relaWh,
                   const float* __restrict__ wa,
                   const float* __restrict__ ba,
                   float* __restrict__ out, int N, int E) {
    const int lane = threadIdx.x & 63;
    const int g = lane >> 4;      // edge-group 0..3
    const int l = lane & 15;      // lane within group
    const int v = (int)((blockIdx.x * blockDim.x + threadIdx.x) >> 6);
    if (v >= N) return;
    const float4 wav = *(const float4*)&wa[l * 4];
    const float bar = ba[0];
    const int start = loff[v] + bsumx[v >> 10];
    const int end = (v + 1 < N) ? (loff[v + 1] + bsumx[(v + 1) >> 10]) : E;

    float4 acc0 = make_float4(0.f, 0.f, 0.f, 0.f);
    float4 acc1 = make_float4(0.f, 0.f, 0.f, 0.f);

    for (int base = start; base < end; base += 8) {
        const int k1 = base + g;
        const int k2 = base + 4 + g;
        const bool va1 = (k1 < end);
        const bool va2 = (k2 < end);
        const int2 rc1 = va1 ? recs[k1] : make_int2(0, 0);
        const int2 rc2 = va2 ? recs[k2] : make_int2(0, 0);
        const int sub1 = rc1.x, rel1 = rc1.y & 0xffff, rid1 = rc1.y >> 16;
        const int sub2 = rc2.x, rel2 = rc2.y & 0xffff, rid2 = rc2.y >> 16;
        const float* sr1 = subrows + (long)sub1 * SS;
        const float* sr2 = subrows + (long)sub2 * SS;

        const ushort4 hw1 = *(const ushort4*)((const unsigned short*)sr1 + l * 4);
        const ushort4 hw2 = *(const ushort4*)((const unsigned short*)sr2 + l * 4);
        const float4 b41 = *(const float4*)&hrWr[rel1 * AA + l * 4];
        const float4 b42 = *(const float4*)&hrWr[rel2 * AA + l * 4];
        const float4 c41 = *(const float4*)&hqrWqr[rid1 * AA + l * 4];
        const float4 c42 = *(const float4*)&hqrWqr[rid2 * AA + l * 4];
        const ushort4 m01 = *(const ushort4*)((const unsigned short*)(sr1 + 32) + l * 8);
        const ushort4 m11 = *(const ushort4*)((const unsigned short*)(sr1 + 32) + l * 8 + 4);
        const ushort4 m02 = *(const ushort4*)((const unsigned short*)(sr2 + 32) + l * 8);
        const ushort4 m12 = *(const ushort4*)((const unsigned short*)(sr2 + 32) + l * 8 + 4);
        const float4 r01 = *(const float4*)&relaWh[rel1 * DD + l * 8];
        const float4 r11 = *(const float4*)&relaWh[rel1 * DD + l * 8 + 4];
        const float4 r02 = *(const float4*)&relaWh[rel2 * DD + l * 8];
        const float4 r12 = *(const float4*)&relaWh[rel2 * DD + l * 8 + 4];

        float s1 = fmaxf(bf2f(hw1.x) + b41.x + c41.x, 0.f) * wav.x;
        s1 = fmaf(fmaxf(bf2f(hw1.y) + b41.y + c41.y, 0.f), wav.y, s1);
        s1 = fmaf(fmaxf(bf2f(hw1.z) + b41.z + c41.z, 0.f), wav.z, s1);
        s1 = fmaf(fmaxf(bf2f(hw1.w) + b41.w + c41.w, 0.f), wav.w, s1);
        float s2 = fmaxf(bf2f(hw2.x) + b42.x + c42.x, 0.f) * wav.x;
        s2 = fmaf(fmaxf(bf2f(hw2.y) + b42.y + c42.y, 0.f), wav.y, s2);
        s2 = fmaf(fmaxf(bf2f(hw2.z) + b42.z + c42.z, 0.f), wav.z, s2);
        s2 = fmaf(fmaxf(bf2f(hw2.w) + b42.w + c42.w, 0.f), wav.w, s2);
        s1 += __shfl_xor(s1, 1);  s2 += __shfl_xor(s2, 1);
        s1 += __shfl_xor(s1, 2);  s2 += __shfl_xor(s2, 2);
        s1 += __shfl_xor(s1, 4);  s2 += __shfl_xor(s2, 4);
        s1 += __shfl_xor(s1, 8);  s2 += __shfl_xor(s2, 8);
        float al1 = __builtin_amdgcn_rcpf(1.0f + __expf(-(s1 + bar)));
        float al2 = __builtin_amdgcn_rcpf(1.0f + __expf(-(s2 + bar)));
        if (!va1) al1 = 0.0f;
        if (!va2) al2 = 0.0f;

        acc0.x = fmaf(al1, bf2f(m01.x) + r01.x, acc0.x);
        acc0.y = fmaf(al1, bf2f(m01.y) + r01.y, acc0.y);
        acc0.z = fmaf(al1, bf2f(m01.z) + r01.z, acc0.z);
        acc0.w = fmaf(al1, bf2f(m01.w) + r01.w, acc0.w);
        acc1.x = fmaf(al1, bf2f(m11.x) + r11.x, acc1.x);
        acc1.y = fmaf(al1, bf2f(m11.y) + r11.y, acc1.y);
        acc1.z = fmaf(al1, bf2f(m11.z) + r11.z, acc1.z);
        acc1.w = fmaf(al1, bf2f(m11.w) + r11.w, acc1.w);
        acc0.x = fmaf(al2, bf2f(m02.x) + r02.x, acc0.x);
        acc0.y = fmaf(al2, bf2f(m02.y) + r02.y, acc0.y);
        acc0.z = fmaf(al2, bf2f(m02.z) + r02.z, acc0.z);
        acc0.w = fmaf(al2, bf2f(m02.w) + r02.w, acc0.w);
        acc1.x = fmaf(al2, bf2f(m12.x) + r12.x, acc1.x);
        acc1.y = fmaf(al2, bf2f(m12.y) + r12.y, acc1.y);
        acc1.z = fmaf(al2, bf2f(m12.z) + r12.z, acc1.z);
        acc1.w = fmaf(al2, bf2f(m12.w) + r12.w, acc1.w);
    }

    #pragma unroll
    for (int o = 16; o <= 32; o <<= 1) {
        acc0.x += __shfl_xor(acc0.x, o);
        acc0.y += __shfl_xor(acc0.y, o);
        acc0.z += __shfl_xor(acc0.z, o);
        acc0.w += __shfl_xor(acc0.w, o);
        acc1.x += __shfl_xor(acc1.x, o);
        acc1.y += __shfl_xor(acc1.y, o);
        acc1.z += __shfl_xor(acc1.z, o);
        acc1.w += __shfl_xor(acc1.w, o);
    }
    if (g == 0) {
        *(float4*)&out[(long)v * DD + l * 8]     = acc0;
        *(float4*)&out[(long)v * DD + l * 8 + 4] = acc1;
    }
}

extern "C" void kernel_launch(void* const* d_in, const int* in_sizes, int n_in,
                              void* d_out, int out_size, void* d_ws, size_t ws_size,
                              hipStream_t stream) {
    // inputs: 0 q_sub (unused), 1 q_rel, 2 hidden, 3 edges, 4 n_node,
    //         5 rela_embed, 6 Ws, 7 Wr, 8 Wqr, 9 bqr, 10 wa, 11 ba, 12 Wh
    const int*   q_rel  = (const int*)d_in[1];
    const float* hidden = (const float*)d_in[2];
    const int*   edges  = (const int*)d_in[3];
    const float* rela   = (const float*)d_in[5];
    const float* Ws     = (const float*)d_in[6];
    const float* Wr     = (const float*)d_in[7];
    const float* Wqr    = (const float*)d_in[8];
    const float* bqr    = (const float*)d_in[9];
    const float* wa     = (const float*)d_in[10];
    const float* ba     = (const float*)d_in[11];
    const float* Wh     = (const float*)d_in[12];

    const int B  = in_sizes[1];
    const int N  = in_sizes[2] / DD;
    const int E  = in_sizes[3] / 6;
    const int NR = in_sizes[5] / DD;

    float* out = (float*)d_out;

    // workspace layout
    float* subrows = (float*)d_ws;                         // N x SS (all bf16 payload)
    float* hrWr    = subrows + (size_t)N * SS;             // NR x 64
    float* relaWh  = hrWr + (size_t)NR * AA;               // NR x 128
    float* hqrWqr  = relaWh + (size_t)NR * DD;             // B x 64
    int*   deg     = (int*)(hqrWqr + (size_t)B * AA);      // N
    int*   done    = deg + N;                              // 1 (zeroed with deg)
    int*   cur     = done + 3;                             // N
    int*   loff    = cur + N;                              // N
    int*   bsum    = loff + N;                             // 64
    int*   bsumx   = bsum + 64;                            // 64
    int2*  recs    = (int2*)(bsumx + 64);                  // E

    const int nA = idiv_up(N, 64);
    const int nB = idiv_up(NR, 64);
    const int nC = idiv_up(B, 64);
    const int nb = idiv_up(N, 1024);

    hipMemsetAsync(deg, 0, (size_t)(N + 1) * sizeof(int), stream);  // deg + done
    proj_all_kernel<<<nA + nB + nC, 256, 0, stream>>>(
        hidden, rela, q_rel, Ws, Wr, Wqr, bqr, Wh,
        subrows, hrWr, relaWh, hqrWqr, N, NR, B, nA, nB);
    hist_kernel<<<idiv_up(E, 1024), 256, 0, stream>>>(edges, deg, E);
    scan_kernel<<<nb, 256, 0, stream>>>(deg, loff, cur, bsum, bsumx, done, N, nb);
    scatter_kernel<<<idiv_up(E, 1024), 256, 0, stream>>>(edges, cur, bsumx, recs, E);
    gather_kernel<<<idiv_up(N * 64, 256), 256, 0, stream>>>(
        recs, loff, bsumx, subrows, hrWr, hqrWqr, relaWh, wa, ba, out, N, E);
}

// Round 9
// 257.223 us; speedup vs baseline: 1.1289x; 1.1289x over previous
//
#include <hip/hip_runtime.h>

#define DD 128
#define AA 64
#define SS 96    // fused sub-row stride in floats: 32 (64 bf16 logit) + 64 (128 bf16 msg)

static inline int idiv_up(int a, int b) { return (a + b - 1) / b; }

__device__ __forceinline__ unsigned short f2bf(float f) {
    unsigned u = __float_as_uint(f);
    u += 0x7fff + ((u >> 16) & 1);          // round-to-nearest-even
    return (unsigned short)(u >> 16);
}
__device__ __forceinline__ float bf2f(unsigned short h) {
    return __uint_as_float(((unsigned)h) << 16);
}

// ---------------------------------------------------------------------------
// Fused projections + histogram, one dispatch.
// Proj blocks: 64 rows x 64 cols of ONE weight stream s:
//   s=0: Ws/Wr/Wqr (ld 64), s=1: Wh cols 0-63, s=2: Wh cols 64-127.
// Inner loop is pure LDS: lht (32KB source tile) + wslice (32KB weight slice).
// 3 consecutive bids share a tile -> lht restage hits L2/L3.
// Hist blocks (tail of grid, ~6%): 4096 edges each, coalesced int4 reads.
// ---------------------------------------------------------------------------
__global__ __launch_bounds__(256)
void proj_hist_kernel(const float* __restrict__ hidden,
                      const float* __restrict__ rela,
                      const int* __restrict__ q_rel,
                      const float* __restrict__ Ws,
                      const float* __restrict__ Wr,
                      const float* __restrict__ Wqr,
                      const float* __restrict__ bqr,
                      const float* __restrict__ Wh,
                      const int* __restrict__ edges,
                      int* __restrict__ deg,
                      float* __restrict__ subrows,
                      float* __restrict__ hrWr,
                      float* __restrict__ relaWh,
                      float* __restrict__ hqrWqr,
                      int N, int NR, int B, int E,
                      int nA, int nB, int nC) {
    __shared__ float lht[128 * 64];     // transposed source tile [d][row]
    __shared__ float wslice[128 * 64];  // weight slice [d][c] for this stream
    const int t = threadIdx.x;
    const int bid = blockIdx.x;
    const int nP = 3 * nA + 3 * nB + nC;

    if (bid >= nP) {
        // ---- histogram tail block: 4096 edges ----
        const int base = (bid - nP) * 4096;
        #pragma unroll
        for (int k = 0; k < 4; ++k) {
            const int e0 = base + (k * 256 + t) * 4;
            if (e0 >= E) break;
            if (e0 + 3 < E) {
                const int4* p = (const int4*)&edges[(long)e0 * 6];
                const int4 j1 = p[1], j2 = p[2], j4 = p[4], j5 = p[5];
                atomicAdd(&deg[j1.y], 1);
                atomicAdd(&deg[j2.w], 1);
                atomicAdd(&deg[j4.y], 1);
                atomicAdd(&deg[j5.w], 1);
            } else {
                for (int e = e0; e < E; ++e) atomicAdd(&deg[edges[(long)e * 6 + 5]], 1);
            }
        }
        return;
    }

    int type, tile, s, nrows;
    const float* src;
    if (bid < 3 * nA)           { type = 0; tile = bid / 3;            s = bid - tile * 3;       nrows = N;  src = hidden; }
    else if (bid < 3 * (nA+nB)) { const int pb = bid - 3 * nA; type = 1; tile = pb / 3; s = pb - tile * 3; nrows = NR; src = rela; }
    else                        { type = 2; tile = bid - 3 * (nA+nB);  s = 0;                    nrows = B;  src = rela; }
    const int rbase = tile * 64;

    // weight stream
    const float* W;
    int ldw, off;
    if (s == 0) { W = (type == 0) ? Ws : (type == 1) ? Wr : Wqr; ldw = 64;  off = 0; }
    else if (s == 1) { W = Wh; ldw = 128; off = 0; }
    else             { W = Wh; ldw = 128; off = 64; }

    // stage weight slice [d][c0..c0+63]
    #pragma unroll
    for (int k = 0; k < 8192; k += 1024) {
        const int f = k + t * 4;
        *(float4*)&wslice[f] = *(const float4*)&W[(long)(f >> 6) * ldw + off + (f & 63)];
    }

    // stage source tile (transposed)
    const int row = t & 63;
    const int d0 = (t >> 6) * 32;
    const int gr = rbase + row;
    const float* srow = nullptr;
    if (gr < nrows) {
        const int sr = (type == 2) ? q_rel[gr] : gr;
        srow = src + (long)sr * DD;
    }
    #pragma unroll
    for (int j = 0; j < 8; ++j) {
        float4 v = make_float4(0.f, 0.f, 0.f, 0.f);
        if (srow) v = *(const float4*)&srow[d0 + j * 4];
        lht[(d0 + j * 4 + 0) * 64 + row] = v.x;
        lht[(d0 + j * 4 + 1) * 64 + row] = v.y;
        lht[(d0 + j * 4 + 2) * 64 + row] = v.z;
        lht[(d0 + j * 4 + 3) * 64 + row] = v.w;
    }
    __syncthreads();

    const int r0 = (t & 15) * 4;
    const int c0 = (t >> 4) * 4;

    float acc[4][4] = {};
    #pragma unroll 4
    for (int d = 0; d < 128; ++d) {
        const float4 hv = *(const float4*)&lht[d * 64 + r0];
        const float4 wv = *(const float4*)&wslice[d * 64 + c0];
        acc[0][0] = fmaf(hv.x, wv.x, acc[0][0]);
        acc[0][1] = fmaf(hv.x, wv.y, acc[0][1]);
        acc[0][2] = fmaf(hv.x, wv.z, acc[0][2]);
        acc[0][3] = fmaf(hv.x, wv.w, acc[0][3]);
        acc[1][0] = fmaf(hv.y, wv.x, acc[1][0]);
        acc[1][1] = fmaf(hv.y, wv.y, acc[1][1]);
        acc[1][2] = fmaf(hv.y, wv.z, acc[1][2]);
        acc[1][3] = fmaf(hv.y, wv.w, acc[1][3]);
        acc[2][0] = fmaf(hv.z, wv.x, acc[2][0]);
        acc[2][1] = fmaf(hv.z, wv.y, acc[2][1]);
        acc[2][2] = fmaf(hv.z, wv.z, acc[2][2]);
        acc[2][3] = fmaf(hv.z, wv.w, acc[2][3]);
        acc[3][0] = fmaf(hv.w, wv.x, acc[3][0]);
        acc[3][1] = fmaf(hv.w, wv.y, acc[3][1]);
        acc[3][2] = fmaf(hv.w, wv.z, acc[3][2]);
        acc[3][3] = fmaf(hv.w, wv.w, acc[3][3]);
    }

    #pragma unroll
    for (int i = 0; i < 4; ++i) {
        const int orow = rbase + r0 + i;
        if (orow >= nrows) continue;
        if (type == 0) {
            float* srw = subrows + (long)orow * SS;
            ushort4 o;
            o.x = f2bf(acc[i][0]); o.y = f2bf(acc[i][1]);
            o.z = f2bf(acc[i][2]); o.w = f2bf(acc[i][3]);
            if (s == 0)      *(ushort4*)((unsigned short*)srw + c0) = o;
            else if (s == 1) *(ushort4*)((unsigned short*)(srw + 32) + c0) = o;
            else             *(ushort4*)((unsigned short*)(srw + 32) + 64 + c0) = o;
        } else if (type == 1) {
            const float4 o = make_float4(acc[i][0], acc[i][1], acc[i][2], acc[i][3]);
            if (s == 0)      *(float4*)&hrWr[(long)orow * 64 + c0] = o;
            else if (s == 1) *(float4*)&relaWh[(long)orow * 128 + c0] = o;
            else             *(float4*)&relaWh[(long)orow * 128 + 64 + c0] = o;
        } else {
            const float4 bq = *(const float4*)&bqr[c0];
            *(float4*)&hqrWqr[(long)orow * 64 + c0] =
                make_float4(acc[i][0] + bq.x, acc[i][1] + bq.y,
                            acc[i][2] + bq.z, acc[i][3] + bq.w);
        }
    }
}

// ---------------------------------------------------------------------------
// One-dispatch scan: per-block local exclusive scan of its 1024-chunk -> loff
// (+ seed cur); last-finished block prefix-scans chunk totals -> bsumx.
// ---------------------------------------------------------------------------
__global__ __launch_bounds__(256)
void scan_kernel(const int* __restrict__ deg, int* __restrict__ loff,
                 int* __restrict__ cur, int* __restrict__ bsum,
                 int* __restrict__ bsumx, int* __restrict__ done,
                 int n, int nb) {
    __shared__ int tsum[256];
    __shared__ int lastFlag;
    const int t = threadIdx.x;
    const int b = blockIdx.x;
    const int base = b * 1024 + t * 4;
    int v[4];
    int s = 0;
    #pragma unroll
    for (int j = 0; j < 4; ++j) {
        v[j] = (base + j < n) ? deg[base + j] : 0;
        s += v[j];
    }
    tsum[t] = s;
    __syncthreads();
    for (int o = 1; o < 256; o <<= 1) {
        const int x = (t >= o) ? tsum[t - o] : 0;
        __syncthreads();
        tsum[t] += x;
        __syncthreads();
    }
    int run = (t > 0) ? tsum[t - 1] : 0;
    #pragma unroll
    for (int j = 0; j < 4; ++j) {
        if (base + j < n) { loff[base + j] = run; cur[base + j] = run; }
        run += v[j];
    }
    if (t == 255) {
        bsum[b] = tsum[255];
        __threadfence();
    }
    __syncthreads();
    if (t == 0) lastFlag = (atomicAdd(done, 1) == nb - 1);
    __syncthreads();
    if (lastFlag && t < 64) {
        __threadfence();
        const int val = (t < nb) ? bsum[t] : 0;
        int inc = val;
        #pragma unroll
        for (int o = 1; o < 64; o <<= 1) {
            const int x = __shfl_up(inc, o, 64);
            if (t >= o) inc += x;
        }
        if (t < nb) bsumx[t] = inc - val;
    }
}

// ---------- scatter: 4 edges/thread, coalesced int4 reads ----------
__global__ void scatter_kernel(const int* __restrict__ edges, int* cur,
                               const int* __restrict__ bsumx,
                               int2* __restrict__ recs, int E) {
    const int e0 = (blockIdx.x * blockDim.x + threadIdx.x) * 4;
    if (e0 >= E) return;
    if (e0 + 3 < E) {
        const int4* p = (const int4*)&edges[(long)e0 * 6];
        const int4 j0 = p[0], j1 = p[1], j2 = p[2], j3 = p[3], j4 = p[4], j5 = p[5];
        {   // e0+0: ridx=0, rel=2, sub=4, obj=5
            const int pos = bsumx[j1.y >> 10] + atomicAdd(&cur[j1.y], 1);
            recs[pos] = make_int2(j1.x, j0.z | (j0.x << 16));
        }
        {   // e0+1: 6,8,10,11
            const int pos = bsumx[j2.w >> 10] + atomicAdd(&cur[j2.w], 1);
            recs[pos] = make_int2(j2.z, j2.x | (j1.z << 16));
        }
        {   // e0+2: 12,14,16,17
            const int pos = bsumx[j4.y >> 10] + atomicAdd(&cur[j4.y], 1);
            recs[pos] = make_int2(j4.x, j3.z | (j3.x << 16));
        }
        {   // e0+3: 18,20,22,23
            const int pos = bsumx[j5.w >> 10] + atomicAdd(&cur[j5.w], 1);
            recs[pos] = make_int2(j5.z, j5.x | (j4.z << 16));
        }
    } else {
        for (int e = e0; e < E; ++e) {
            const int* ed = edges + (long)e * 6;
            const int obj = ed[5];
            const int pos = bsumx[obj >> 10] + atomicAdd(&cur[obj], 1);
            recs[pos] = make_int2(ed[4], ed[2] | (ed[0] << 16));
        }
    }
}

// ---------------------------------------------------------------------------
// Gather: one wave per destination node, 16 lanes per edge, 8 edges in flight.
// ---------------------------------------------------------------------------
__global__ __launch_bounds__(256)
void gather_kernel(const int2* __restrict__ recs,
                   const int* __restrict__ loff,
                   const int* __restrict__ bsumx,
                   const float* __restrict__ subrows,
                   const float* __restrict__ hrWr,
                   const float* __restrict__ hqrWqr,
                   const float* __restrict__ relaWh,
                   const float* __restrict__ wa,
                   const float* __restrict__ ba,
                   float* __restrict__ out, int N, int E) {
    const int lane = threadIdx.x & 63;
    const int g = lane >> 4;      // edge-group 0..3
    const int l = lane & 15;      // lane within group
    const int v = (int)((blockIdx.x * blockDim.x + threadIdx.x) >> 6);
    if (v >= N) return;
    const float4 wav = *(const float4*)&wa[l * 4];
    const float bar = ba[0];
    const int start = loff[v] + bsumx[v >> 10];
    const int end = (v + 1 < N) ? (loff[v + 1] + bsumx[(v + 1) >> 10]) : E;

    float4 acc0 = make_float4(0.f, 0.f, 0.f, 0.f);
    float4 acc1 = make_float4(0.f, 0.f, 0.f, 0.f);

    for (int base = start; base < end; base += 8) {
        const int k1 = base + g;
        const int k2 = base + 4 + g;
        const bool va1 = (k1 < end);
        const bool va2 = (k2 < end);
        const int2 rc1 = va1 ? recs[k1] : make_int2(0, 0);
        const int2 rc2 = va2 ? recs[k2] : make_int2(0, 0);
        const int sub1 = rc1.x, rel1 = rc1.y & 0xffff, rid1 = rc1.y >> 16;
        const int sub2 = rc2.x, rel2 = rc2.y & 0xffff, rid2 = rc2.y >> 16;
        const float* sr1 = subrows + (long)sub1 * SS;
        const float* sr2 = subrows + (long)sub2 * SS;

        const ushort4 hw1 = *(const ushort4*)((const unsigned short*)sr1 + l * 4);
        const ushort4 hw2 = *(const ushort4*)((const unsigned short*)sr2 + l * 4);
        const float4 b41 = *(const float4*)&hrWr[rel1 * AA + l * 4];
        const float4 b42 = *(const float4*)&hrWr[rel2 * AA + l * 4];
        const float4 c41 = *(const float4*)&hqrWqr[rid1 * AA + l * 4];
        const float4 c42 = *(const float4*)&hqrWqr[rid2 * AA + l * 4];
        const ushort4 m01 = *(const ushort4*)((const unsigned short*)(sr1 + 32) + l * 8);
        const ushort4 m11 = *(const ushort4*)((const unsigned short*)(sr1 + 32) + l * 8 + 4);
        const ushort4 m02 = *(const ushort4*)((const unsigned short*)(sr2 + 32) + l * 8);
        const ushort4 m12 = *(const ushort4*)((const unsigned short*)(sr2 + 32) + l * 8 + 4);
        const float4 r01 = *(const float4*)&relaWh[rel1 * DD + l * 8];
        const float4 r11 = *(const float4*)&relaWh[rel1 * DD + l * 8 + 4];
        const float4 r02 = *(const float4*)&relaWh[rel2 * DD + l * 8];
        const float4 r12 = *(const float4*)&relaWh[rel2 * DD + l * 8 + 4];

        float s1 = fmaxf(bf2f(hw1.x) + b41.x + c41.x, 0.f) * wav.x;
        s1 = fmaf(fmaxf(bf2f(hw1.y) + b41.y + c41.y, 0.f), wav.y, s1);
        s1 = fmaf(fmaxf(bf2f(hw1.z) + b41.z + c41.z, 0.f), wav.z, s1);
        s1 = fmaf(fmaxf(bf2f(hw1.w) + b41.w + c41.w, 0.f), wav.w, s1);
        float s2 = fmaxf(bf2f(hw2.x) + b42.x + c42.x, 0.f) * wav.x;
        s2 = fmaf(fmaxf(bf2f(hw2.y) + b42.y + c42.y, 0.f), wav.y, s2);
        s2 = fmaf(fmaxf(bf2f(hw2.z) + b42.z + c42.z, 0.f), wav.z, s2);
        s2 = fmaf(fmaxf(bf2f(hw2.w) + b42.w + c42.w, 0.f), wav.w, s2);
        s1 += __shfl_xor(s1, 1);  s2 += __shfl_xor(s2, 1);
        s1 += __shfl_xor(s1, 2);  s2 += __shfl_xor(s2, 2);
        s1 += __shfl_xor(s1, 4);  s2 += __shfl_xor(s2, 4);
        s1 += __shfl_xor(s1, 8);  s2 += __shfl_xor(s2, 8);
        float al1 = __builtin_amdgcn_rcpf(1.0f + __expf(-(s1 + bar)));
        float al2 = __builtin_amdgcn_rcpf(1.0f + __expf(-(s2 + bar)));
        if (!va1) al1 = 0.0f;
        if (!va2) al2 = 0.0f;

        acc0.x = fmaf(al1, bf2f(m01.x) + r01.x, acc0.x);
        acc0.y = fmaf(al1, bf2f(m01.y) + r01.y, acc0.y);
        acc0.z = fmaf(al1, bf2f(m01.z) + r01.z, acc0.z);
        acc0.w = fmaf(al1, bf2f(m01.w) + r01.w, acc0.w);
        acc1.x = fmaf(al1, bf2f(m11.x) + r11.x, acc1.x);
        acc1.y = fmaf(al1, bf2f(m11.y) + r11.y, acc1.y);
        acc1.z = fmaf(al1, bf2f(m11.z) + r11.z, acc1.z);
        acc1.w = fmaf(al1, bf2f(m11.w) + r11.w, acc1.w);
        acc0.x = fmaf(al2, bf2f(m02.x) + r02.x, acc0.x);
        acc0.y = fmaf(al2, bf2f(m02.y) + r02.y, acc0.y);
        acc0.z = fmaf(al2, bf2f(m02.z) + r02.z, acc0.z);
        acc0.w = fmaf(al2, bf2f(m02.w) + r02.w, acc0.w);
        acc1.x = fmaf(al2, bf2f(m12.x) + r12.x, acc1.x);
        acc1.y = fmaf(al2, bf2f(m12.y) + r12.y, acc1.y);
        acc1.z = fmaf(al2, bf2f(m12.z) + r12.z, acc1.z);
        acc1.w = fmaf(al2, bf2f(m12.w) + r12.w, acc1.w);
    }

    #pragma unroll
    for (int o = 16; o <= 32; o <<= 1) {
        acc0.x += __shfl_xor(acc0.x, o);
        acc0.y += __shfl_xor(acc0.y, o);
        acc0.z += __shfl_xor(acc0.z, o);
        acc0.w += __shfl_xor(acc0.w, o);
        acc1.x += __shfl_xor(acc1.x, o);
        acc1.y += __shfl_xor(acc1.y, o);
        acc1.z += __shfl_xor(acc1.z, o);
        acc1.w += __shfl_xor(acc1.w, o);
    }
    if (g == 0) {
        *(float4*)&out[(long)v * DD + l * 8]     = acc0;
        *(float4*)&out[(long)v * DD + l * 8 + 4] = acc1;
    }
}

extern "C" void kernel_launch(void* const* d_in, const int* in_sizes, int n_in,
                              void* d_out, int out_size, void* d_ws, size_t ws_size,
                              hipStream_t stream) {
    // inputs: 0 q_sub (unused), 1 q_rel, 2 hidden, 3 edges, 4 n_node,
    //         5 rela_embed, 6 Ws, 7 Wr, 8 Wqr, 9 bqr, 10 wa, 11 ba, 12 Wh
    const int*   q_rel  = (const int*)d_in[1];
    const float* hidden = (const float*)d_in[2];
    const int*   edges  = (const int*)d_in[3];
    const float* rela   = (const float*)d_in[5];
    const float* Ws     = (const float*)d_in[6];
    const float* Wr     = (const float*)d_in[7];
    const float* Wqr    = (const float*)d_in[8];
    const float* bqr    = (const float*)d_in[9];
    const float* wa     = (const float*)d_in[10];
    const float* ba     = (const float*)d_in[11];
    const float* Wh     = (const float*)d_in[12];

    const int B  = in_sizes[1];
    const int N  = in_sizes[2] / DD;
    const int E  = in_sizes[3] / 6;
    const int NR = in_sizes[5] / DD;

    float* out = (float*)d_out;

    // workspace layout
    float* subrows = (float*)d_ws;                         // N x SS (all bf16 payload)
    float* hrWr    = subrows + (size_t)N * SS;             // NR x 64
    float* relaWh  = hrWr + (size_t)NR * AA;               // NR x 128
    float* hqrWqr  = relaWh + (size_t)NR * DD;             // B x 64
    int*   deg     = (int*)(hqrWqr + (size_t)B * AA);      // N
    int*   done    = deg + N;                              // 1 (zeroed with deg)
    int*   cur     = done + 3;                             // N
    int*   loff    = cur + N;                              // N
    int*   bsum    = loff + N;                             // 64
    int*   bsumx   = bsum + 64;                            // 64
    int2*  recs    = (int2*)(bsumx + 64);                  // E

    const int nA = idiv_up(N, 64);
    const int nB = idiv_up(NR, 64);
    const int nC = idiv_up(B, 64);
    const int nH = idiv_up(E, 4096);
    const int nb = idiv_up(N, 1024);
    const int grid_ph = 3 * nA + 3 * nB + nC + nH;

    hipMemsetAsync(deg, 0, (size_t)(N + 1) * sizeof(int), stream);  // deg + done
    proj_hist_kernel<<<grid_ph, 256, 0, stream>>>(
        hidden, rela, q_rel, Ws, Wr, Wqr, bqr, Wh, edges, deg,
        subrows, hrWr, relaWh, hqrWqr, N, NR, B, E, nA, nB, nC);
    scan_kernel<<<nb, 256, 0, stream>>>(deg, loff, cur, bsum, bsumx, done, N, nb);
    scatter_kernel<<<idiv_up(E, 1024), 256, 0, stream>>>(edges, cur, bsumx, recs, E);
    gather_kernel<<<idiv_up(N * 64, 256), 256, 0, stream>>>(
        recs, loff, bsumx, subrows, hrWr, hqrWqr, relaWh, wa, ba, out, N, E);
}